// Round 2
// baseline (114.890 us; speedup 1.0000x reference)
//
#include <hip/hip_runtime.h>
#include <hip/hip_bf16.h>

#define BATCH 4096
#define NROWS 8192
#define DIM   128

typedef __bf16 bf16x8 __attribute__((ext_vector_type(8)));
typedef __bf16 bf16x2 __attribute__((ext_vector_type(2)));
typedef float  f32x4  __attribute__((ext_vector_type(4)));

// ---------------------------------------------------------------------------
// Kernel 1: row-normalize z = concat(zx, zy) -> bf16 zn [8192 x 128],
// and zero S[row] (removes a separate memset dispatch).
// One wave per row; lane holds 2 floats.
// ---------------------------------------------------------------------------
__global__ __launch_bounds__(256) void normalize_kernel(
    const float* __restrict__ zx, const float* __restrict__ zy,
    ushort* __restrict__ zn, float* __restrict__ S)
{
  const int tid  = threadIdx.x;
  const int lane = tid & 63;
  const int w    = tid >> 6;
  const int row  = blockIdx.x * 4 + w;
  const float* src = (row < BATCH) ? (zx + (size_t)row * DIM)
                                   : (zy + (size_t)(row - BATCH) * DIM);
  float2 v = ((const float2*)src)[lane];
  float ss = v.x * v.x + v.y * v.y;
#pragma unroll
  for (int off = 1; off < 64; off <<= 1)
    ss += __shfl_xor(ss, off, 64);
  float inv = 1.0f / fmaxf(sqrtf(ss), 1e-8f);
  bf16x2 st;
  st.x = (__bf16)(v.x * inv);
  st.y = (__bf16)(v.y * inv);
  reinterpret_cast<bf16x2*>(zn + (size_t)row * DIM)[lane] = st;
  if (lane == 0) S[row] = 0.f;
}

// ---------------------------------------------------------------------------
// Kernel 2: symmetric fused sim-GEMM + exp-sum epilogue.
// One block per upper-triangular 128x128 tile pair (rb <= cb), 2080 blocks.
// No LDS, no barriers: A and B fragments load straight from L2-resident zn
// (2 MB). Off-diagonal tiles contribute exp(sim-2) to BOTH row sums S[i]
// and col sums S[j] (symmetry => half the MFMA work). Diagonal tiles mask
// rl==cl and contribute row sums only. Partner tiles (cb == rb+32) emit
// P[i] = sim[i, i^4096] for both halves.
// ---------------------------------------------------------------------------
__global__ __launch_bounds__(256) void simloss_kernel(
    const ushort* __restrict__ zn, float* __restrict__ S, float* __restrict__ P)
{
  const int tid  = threadIdx.x;
  const int lane = tid & 63;
  const int w    = tid >> 6;
  const int wr   = w >> 1, wc = w & 1;
  const int q    = lane >> 4;
  const int l15  = lane & 15;

  // triangular decode: Offset(rb) = rb*(129-rb)/2
  const int t = blockIdx.x;
  int rb = (int)(0.5f * (129.0f - sqrtf((float)(16641 - 8 * t))));
  while (rb * (129 - rb) / 2 > t) --rb;
  while ((rb + 1) * (128 - rb) / 2 <= t) ++rb;
  const int cb = rb + (t - rb * (129 - rb) / 2);

  const int R0 = rb * 128, C0 = cb * 128;
  const int abase = (R0 + wr * 64 + l15) * DIM + q * 8;
  const int bbase = (C0 + wc * 64 + l15) * DIM + q * 8;

  f32x4 acc[4][4];
#pragma unroll
  for (int mi = 0; mi < 4; ++mi)
#pragma unroll
    for (int ni = 0; ni < 4; ++ni)
      acc[mi][ni] = (f32x4){0.f, 0.f, 0.f, 0.f};

#pragma unroll
  for (int ks = 0; ks < 4; ++ks) {
    bf16x8 af[4], bf[4];
#pragma unroll
    for (int mi = 0; mi < 4; ++mi)
      af[mi] = *reinterpret_cast<const bf16x8*>(zn + abase + mi * 16 * DIM + ks * 32);
#pragma unroll
    for (int ni = 0; ni < 4; ++ni)
      bf[ni] = *reinterpret_cast<const bf16x8*>(zn + bbase + ni * 16 * DIM + ks * 32);
#pragma unroll
    for (int mi = 0; mi < 4; ++mi)
#pragma unroll
      for (int ni = 0; ni < 4; ++ni)
        acc[mi][ni] = __builtin_amdgcn_mfma_f32_16x16x32_bf16(
            af[mi], bf[ni], acc[mi][ni], 0, 0, 0);
  }

  const float K1 = 2.8853900817779268f;  // (1/TEMP)*log2(e); shift -2 folded
  const bool diag = (rb == cb);
  const bool part = (cb == rb + 32);

  float Srow[4][4];
  float Scol[4];
#pragma unroll
  for (int mi = 0; mi < 4; ++mi)
#pragma unroll
    for (int r = 0; r < 4; ++r) Srow[mi][r] = 0.f;
#pragma unroll
  for (int ni = 0; ni < 4; ++ni) Scol[ni] = 0.f;

#pragma unroll
  for (int mi = 0; mi < 4; ++mi)
#pragma unroll
    for (int ni = 0; ni < 4; ++ni)
#pragma unroll
      for (int r = 0; r < 4; ++r) {
        const float d = acc[mi][ni][r];
        float v = __builtin_amdgcn_exp2f(fmaf(d, K1, -K1));
        const int rl = wr * 64 + mi * 16 + q * 4 + r;
        const int cl = wc * 64 + ni * 16 + l15;
        if (diag && rl == cl) v = 0.f;
        Srow[mi][r] += v;
        Scol[ni] += v;
        if (part && rl == cl) {
          const float p = 2.0f * d;
          P[R0 + rl] = p;
          P[C0 + cl] = p;
        }
      }

  // row sums: reduce over l15 (16 cols per lane-group), one atomic per row
#pragma unroll
  for (int mi = 0; mi < 4; ++mi)
#pragma unroll
    for (int r = 0; r < 4; ++r) {
      float v = Srow[mi][r];
      v += __shfl_xor(v, 1, 64);
      v += __shfl_xor(v, 2, 64);
      v += __shfl_xor(v, 4, 64);
      v += __shfl_xor(v, 8, 64);
      if (l15 == 0)
        atomicAdd(&S[R0 + wr * 64 + mi * 16 + q * 4 + r], v);
    }

  // col sums (symmetric contribution): reduce over q, skip on diagonal tiles
  if (!diag) {
#pragma unroll
    for (int ni = 0; ni < 4; ++ni) {
      float v = Scol[ni];
      v += __shfl_xor(v, 16, 64);
      v += __shfl_xor(v, 32, 64);
      if (q == 0)
        atomicAdd(&S[C0 + wc * 64 + ni * 16 + l15], v);
    }
  }
}

// ---------------------------------------------------------------------------
// Kernel 3: loss = mean_i( 2 + log(S_i) - P_i ). Single block, direct write.
// ---------------------------------------------------------------------------
__global__ __launch_bounds__(1024) void finalize_kernel(
    const float* __restrict__ S, const float* __restrict__ P,
    float* __restrict__ out)
{
  float c = 0.f;
  for (int i = threadIdx.x; i < NROWS; i += 1024)
    c += 2.0f + logf(S[i]) - P[i];
#pragma unroll
  for (int off = 1; off < 64; off <<= 1)
    c += __shfl_xor(c, off, 64);
  __shared__ float wsum[16];
  const int lane = threadIdx.x & 63, w = threadIdx.x >> 6;
  if (lane == 0) wsum[w] = c;
  __syncthreads();
  if (threadIdx.x == 0) {
    float s = 0.f;
#pragma unroll
    for (int k = 0; k < 16; ++k) s += wsum[k];
    out[0] = s * (1.0f / NROWS);
  }
}

// ---------------------------------------------------------------------------
extern "C" void kernel_launch(void* const* d_in, const int* in_sizes, int n_in,
                              void* d_out, int out_size, void* d_ws, size_t ws_size,
                              hipStream_t stream)
{
  const float* zx = (const float*)d_in[0];
  const float* zy = (const float*)d_in[1];
  ushort* zn = (ushort*)d_ws;                                   // 2 MiB bf16
  float*  S  = (float*)((char*)d_ws + (size_t)NROWS * DIM * 2); // 32 KiB
  float*  P  = S + NROWS;                                       // 32 KiB
  float*  out = (float*)d_out;

  normalize_kernel<<<NROWS / 4, 256, 0, stream>>>(zx, zy, zn, S);
  simloss_kernel<<<2080, 256, 0, stream>>>(zn, S, P);
  finalize_kernel<<<1, 1024, 0, stream>>>(S, P, out);
}

// Round 3
// 107.052 us; speedup vs baseline: 1.0732x; 1.0732x over previous
//
#include <hip/hip_runtime.h>
#include <hip/hip_bf16.h>

#define BATCH 4096
#define NROWS 8192
#define DIM   128

typedef __bf16 bf16x8 __attribute__((ext_vector_type(8)));
typedef __bf16 bf16x2 __attribute__((ext_vector_type(2)));
typedef float  f32x4  __attribute__((ext_vector_type(4)));

typedef const __attribute__((address_space(1))) unsigned int* gptr_t;
typedef __attribute__((address_space(3))) unsigned int* lptr_t;

// ---------------------------------------------------------------------------
// Kernel 1: row-normalize z = concat(zx, zy) -> bf16 zn [8192 x 128],
// and zero S[row]. One wave per row; lane holds 2 floats.
// ---------------------------------------------------------------------------
__global__ __launch_bounds__(256) void normalize_kernel(
    const float* __restrict__ zx, const float* __restrict__ zy,
    ushort* __restrict__ zn, float* __restrict__ S)
{
  const int tid  = threadIdx.x;
  const int lane = tid & 63;
  const int w    = tid >> 6;
  const int row  = blockIdx.x * 4 + w;
  const float* src = (row < BATCH) ? (zx + (size_t)row * DIM)
                                   : (zy + (size_t)(row - BATCH) * DIM);
  float2 v = ((const float2*)src)[lane];
  float ss = v.x * v.x + v.y * v.y;
#pragma unroll
  for (int off = 1; off < 64; off <<= 1)
    ss += __shfl_xor(ss, off, 64);
  float inv = 1.0f / fmaxf(sqrtf(ss), 1e-8f);
  bf16x2 st;
  st.x = (__bf16)(v.x * inv);
  st.y = (__bf16)(v.y * inv);
  reinterpret_cast<bf16x2*>(zn + (size_t)row * DIM)[lane] = st;
  if (lane == 0) S[row] = 0.f;
}

// ---------------------------------------------------------------------------
// Kernel 2: symmetric fused sim-GEMM + exp-sum epilogue, one block per
// upper-triangular 128x128 tile pair (rb <= cb), 2080 blocks (~8/CU queued).
// Both tiles staged to LDS via coalesced global_load_lds (16B chunks, XOR
// swizzle); ONE barrier; fragments via ds_read_b128. Off-diagonal tiles feed
// both row sums S[i] and col sums S[j] (symmetry halves MFMA work).
// ---------------------------------------------------------------------------
__global__ __launch_bounds__(256) void simloss_kernel(
    const ushort* __restrict__ zn, float* __restrict__ S, float* __restrict__ P)
{
  __shared__ ushort As[128 * 128];   // 32 KiB, swizzled 16B-chunk layout
  __shared__ ushort Bs[128 * 128];   // 32 KiB

  const int tid  = threadIdx.x;
  const int lane = tid & 63;
  const int w    = tid >> 6;
  const int wr   = w >> 1, wc = w & 1;
  const int q    = lane >> 4;
  const int l15  = lane & 15;

  // triangular decode: Offset(rb) = rb*(129-rb)/2
  const int t = blockIdx.x;
  int rb = (int)(0.5f * (129.0f - sqrtf((float)(16641 - 8 * t))));
  while (rb * (129 - rb) / 2 > t) --rb;
  while ((rb + 1) * (128 - rb) / 2 <= t) ++rb;
  const int cb = rb + (t - rb * (129 - rb) / 2);

  const int R0 = rb * 128, C0 = cb * 128;
  const bool diag = (rb == cb);
  const bool part = (cb == rb + 32);

  // Stage A tile (and B tile if off-diagonal). Chunk (row,c) lands at LDS
  // chunk row*16 + (c ^ (row&15)); dest = wave-uniform base + lane*16.
#pragma unroll
  for (int j = 0; j < 8; ++j) {
    const int Lbase = w * 512 + j * 64;
    const int row   = w * 32 + j * 4 + q;
    const int c     = l15 ^ (row & 15);
    const ushort* g = zn + (size_t)(R0 + row) * DIM + c * 8;
    __builtin_amdgcn_global_load_lds((gptr_t)g, (lptr_t)(As + Lbase * 8), 16, 0, 0);
  }
  if (!diag) {
#pragma unroll
    for (int j = 0; j < 8; ++j) {
      const int Lbase = w * 512 + j * 64;
      const int row   = w * 32 + j * 4 + q;
      const int c     = l15 ^ (row & 15);
      const ushort* g = zn + (size_t)(C0 + row) * DIM + c * 8;
      __builtin_amdgcn_global_load_lds((gptr_t)g, (lptr_t)(Bs + Lbase * 8), 16, 0, 0);
    }
  }
  __syncthreads();

  const ushort* Bsrc = diag ? As : Bs;

  f32x4 acc[4][4];
#pragma unroll
  for (int mi = 0; mi < 4; ++mi)
#pragma unroll
    for (int ni = 0; ni < 4; ++ni)
      acc[mi][ni] = (f32x4){0.f, 0.f, 0.f, 0.f};

#pragma unroll
  for (int ks = 0; ks < 4; ++ks) {
    const int ck = ks * 4 + q;
    bf16x8 af[4], bf[4];
#pragma unroll
    for (int mi = 0; mi < 4; ++mi) {
      const int nl = wr * 64 + mi * 16 + l15;
      af[mi] = *reinterpret_cast<const bf16x8*>(As + (nl * 16 + (ck ^ (nl & 15))) * 8);
    }
#pragma unroll
    for (int ni = 0; ni < 4; ++ni) {
      const int nl = wc * 64 + ni * 16 + l15;
      bf[ni] = *reinterpret_cast<const bf16x8*>(Bsrc + (nl * 16 + (ck ^ (nl & 15))) * 8);
    }
#pragma unroll
    for (int mi = 0; mi < 4; ++mi)
#pragma unroll
      for (int ni = 0; ni < 4; ++ni)
        acc[mi][ni] = __builtin_amdgcn_mfma_f32_16x16x32_bf16(
            af[mi], bf[ni], acc[mi][ni], 0, 0, 0);
  }

  const float K1 = 2.8853900817779268f;  // (1/TEMP)*log2(e); shift -2 folded

  float Srow[4][4];
  float Scol[4];
#pragma unroll
  for (int mi = 0; mi < 4; ++mi)
#pragma unroll
    for (int r = 0; r < 4; ++r) Srow[mi][r] = 0.f;
#pragma unroll
  for (int ni = 0; ni < 4; ++ni) Scol[ni] = 0.f;

#pragma unroll
  for (int mi = 0; mi < 4; ++mi)
#pragma unroll
    for (int ni = 0; ni < 4; ++ni)
#pragma unroll
      for (int r = 0; r < 4; ++r) {
        const float d = acc[mi][ni][r];
        float v = __builtin_amdgcn_exp2f(fmaf(d, K1, -K1));
        const int rl = wr * 64 + mi * 16 + q * 4 + r;
        const int cl = wc * 64 + ni * 16 + l15;
        if (diag && rl == cl) v = 0.f;
        Srow[mi][r] += v;
        Scol[ni] += v;
        if (part && rl == cl) {
          const float p = 2.0f * d;
          P[R0 + rl] = p;
          P[C0 + cl] = p;
        }
      }

  // row sums: reduce over l15, one atomic per row
#pragma unroll
  for (int mi = 0; mi < 4; ++mi)
#pragma unroll
    for (int r = 0; r < 4; ++r) {
      float v = Srow[mi][r];
      v += __shfl_xor(v, 1, 64);
      v += __shfl_xor(v, 2, 64);
      v += __shfl_xor(v, 4, 64);
      v += __shfl_xor(v, 8, 64);
      if (l15 == 0)
        atomicAdd(&S[R0 + wr * 64 + mi * 16 + q * 4 + r], v);
    }

  // col sums (symmetric contribution): reduce over q, skip on diagonal tiles
  if (!diag) {
#pragma unroll
    for (int ni = 0; ni < 4; ++ni) {
      float v = Scol[ni];
      v += __shfl_xor(v, 16, 64);
      v += __shfl_xor(v, 32, 64);
      if (q == 0)
        atomicAdd(&S[C0 + wc * 64 + ni * 16 + l15], v);
    }
  }
}

// ---------------------------------------------------------------------------
// Kernel 3: loss = mean_i( 2 + log(S_i) - P_i ). Single block, direct write.
// ---------------------------------------------------------------------------
__global__ __launch_bounds__(1024) void finalize_kernel(
    const float* __restrict__ S, const float* __restrict__ P,
    float* __restrict__ out)
{
  float c = 0.f;
  for (int i = threadIdx.x; i < NROWS; i += 1024)
    c += 2.0f + logf(S[i]) - P[i];
#pragma unroll
  for (int off = 1; off < 64; off <<= 1)
    c += __shfl_xor(c, off, 64);
  __shared__ float wsum[16];
  const int lane = threadIdx.x & 63, w = threadIdx.x >> 6;
  if (lane == 0) wsum[w] = c;
  __syncthreads();
  if (threadIdx.x == 0) {
    float s = 0.f;
#pragma unroll
    for (int k = 0; k < 16; ++k) s += wsum[k];
    out[0] = s * (1.0f / NROWS);
  }
}

// ---------------------------------------------------------------------------
extern "C" void kernel_launch(void* const* d_in, const int* in_sizes, int n_in,
                              void* d_out, int out_size, void* d_ws, size_t ws_size,
                              hipStream_t stream)
{
  const float* zx = (const float*)d_in[0];
  const float* zy = (const float*)d_in[1];
  ushort* zn = (ushort*)d_ws;                                   // 2 MiB bf16
  float*  S  = (float*)((char*)d_ws + (size_t)NROWS * DIM * 2); // 32 KiB
  float*  P  = S + NROWS;                                       // 32 KiB
  float*  out = (float*)d_out;

  normalize_kernel<<<NROWS / 4, 256, 0, stream>>>(zx, zy, zn, S);
  simloss_kernel<<<2080, 256, 0, stream>>>(zn, S, P);
  finalize_kernel<<<1, 1024, 0, stream>>>(S, P, out);
}

// Round 4
// 89.224 us; speedup vs baseline: 1.2876x; 1.1998x over previous
//
#include <hip/hip_runtime.h>
#include <hip/hip_bf16.h>

#define BATCH 4096
#define NROWS 8192
#define DIM   128

typedef __bf16 bf16x8 __attribute__((ext_vector_type(8)));
typedef __bf16 bf16x2 __attribute__((ext_vector_type(2)));
typedef float  f32x4  __attribute__((ext_vector_type(4)));

typedef const __attribute__((address_space(1))) unsigned int* gptr_t;
typedef __attribute__((address_space(3))) unsigned int* lptr_t;

// ---------------------------------------------------------------------------
// Kernel 1: row-normalize z = concat(zx, zy) -> bf16 zn [8192 x 128],
// and zero S[row]. One wave per row; lane holds 2 floats.
// ---------------------------------------------------------------------------
__global__ __launch_bounds__(256) void normalize_kernel(
    const float* __restrict__ zx, const float* __restrict__ zy,
    ushort* __restrict__ zn, float* __restrict__ S)
{
  const int tid  = threadIdx.x;
  const int lane = tid & 63;
  const int w    = tid >> 6;
  const int row  = blockIdx.x * 4 + w;
  const float* src = (row < BATCH) ? (zx + (size_t)row * DIM)
                                   : (zy + (size_t)(row - BATCH) * DIM);
  float2 v = ((const float2*)src)[lane];
  float ss = v.x * v.x + v.y * v.y;
#pragma unroll
  for (int off = 1; off < 64; off <<= 1)
    ss += __shfl_xor(ss, off, 64);
  float inv = 1.0f / fmaxf(sqrtf(ss), 1e-8f);
  bf16x2 st;
  st.x = (__bf16)(v.x * inv);
  st.y = (__bf16)(v.y * inv);
  reinterpret_cast<bf16x2*>(zn + (size_t)row * DIM)[lane] = st;
  if (lane == 0) S[row] = 0.f;
}

// ---------------------------------------------------------------------------
// Kernel 2: symmetric fused sim-GEMM + exp-sum, strip-pipelined.
// Block (rb, c) handles col-tiles cb0=rb+4c .. min(cb0+3, 63); 544 valid
// blocks. A tile staged once -> fragments in registers; B tiles stream
// through double-buffered LDS with prefetch overlapping compute. Row sums
// accumulate in registers across the strip (one atomic set per block);
// col sums (symmetry) reduced+atomic per tile. Diag tile (chunk 0) computed
// from the A buffer with self-term post-subtraction.
// ---------------------------------------------------------------------------
__global__ __launch_bounds__(256, 2) void simloss_kernel(
    const ushort* __restrict__ zn, float* __restrict__ S, float* __restrict__ P)
{
  __shared__ ushort Ls[2][128 * 128];   // 2 x 32 KiB, swizzled 16B-chunk layout

  const int rb  = blockIdx.x;                 // 0..63
  const int cb0 = rb + (int)blockIdx.y * 4;   // first col-tile of strip
  if (cb0 > 63) return;
  const int ntiles   = min(4, 64 - cb0);
  const bool havediag = (blockIdx.y == 0);    // strip starts at the diagonal

  const int tid  = threadIdx.x;
  const int lane = tid & 63;
  const int w    = tid >> 6;
  const int wr   = w >> 1, wc = w & 1;
  const int q    = lane >> 4;
  const int l15  = lane & 15;
  const int R0   = rb * 128;
  const float K1 = 2.8853900817779268f;  // (1/TEMP)*log2(e); shift -2 folded

  // Coalesced stage of 128x128 bf16 tile 'tb' into LDS buffer. Chunk (row,c)
  // lands at LDS chunk row*16 + (c ^ (row&15)); dest = uniform base + lane*16.
  auto stage = [&](int tb, ushort* buf) {
#pragma unroll
    for (int j = 0; j < 8; ++j) {
      const int Lbase = w * 512 + j * 64;
      const int row   = w * 32 + j * 4 + q;
      const int c     = l15 ^ (row & 15);
      const ushort* g = zn + (size_t)(tb * 128 + row) * DIM + c * 8;
      __builtin_amdgcn_global_load_lds((gptr_t)g, (lptr_t)(buf + Lbase * 8), 16, 0, 0);
    }
  };

  stage(rb, Ls[0]);
  __syncthreads();

  // A fragments: rows R0 + wr*64 + mi*16 + l15, k-chunk ks*4+q
  bf16x8 af[4][4];
#pragma unroll
  for (int ks = 0; ks < 4; ++ks) {
    const int ck = ks * 4 + q;
#pragma unroll
    for (int mi = 0; mi < 4; ++mi) {
      const int nl = wr * 64 + mi * 16 + l15;
      af[mi][ks] = *reinterpret_cast<const bf16x8*>(Ls[0] + (nl * 16 + (ck ^ (nl & 15))) * 8);
    }
  }

  float Srow[4][4];
#pragma unroll
  for (int mi = 0; mi < 4; ++mi)
#pragma unroll
    for (int r = 0; r < 4; ++r) Srow[mi][r] = 0.f;

  const int first = havediag ? 1 : 0;
  // Prefetch first streamed B tile; overlaps the diag compute below.
  if (first < ntiles) stage(cb0 + first, Ls[1]);

  if (havediag) {
    // Diagonal tile: B fragments read from the A buffer (same rows).
    f32x4 acc[4][4];
#pragma unroll
    for (int mi = 0; mi < 4; ++mi)
#pragma unroll
      for (int ni = 0; ni < 4; ++ni)
        acc[mi][ni] = (f32x4){0.f, 0.f, 0.f, 0.f};
#pragma unroll
    for (int ks = 0; ks < 4; ++ks) {
      const int ck = ks * 4 + q;
      bf16x8 bf[4];
#pragma unroll
      for (int ni = 0; ni < 4; ++ni) {
        const int nl = wc * 64 + ni * 16 + l15;
        bf[ni] = *reinterpret_cast<const bf16x8*>(Ls[0] + (nl * 16 + (ck ^ (nl & 15))) * 8);
      }
#pragma unroll
      for (int mi = 0; mi < 4; ++mi)
#pragma unroll
        for (int ni = 0; ni < 4; ++ni)
          acc[mi][ni] = __builtin_amdgcn_mfma_f32_16x16x32_bf16(
              af[mi][ks], bf[ni], acc[mi][ni], 0, 0, 0);
    }
    // Row sums only (tile is symmetric: col sums == row sums, and all 128x128
    // entries of the diag tile are computed here).
#pragma unroll
    for (int mi = 0; mi < 4; ++mi)
#pragma unroll
      for (int ni = 0; ni < 4; ++ni)
#pragma unroll
        for (int r = 0; r < 4; ++r)
          Srow[mi][r] += __builtin_amdgcn_exp2f(fmaf(acc[mi][ni][r], K1, -K1));
    // Subtract the self-similarity term (rl==cl exists only when wr==wc).
    if (wr == wc) {
#pragma unroll
      for (int mi = 0; mi < 4; ++mi)
#pragma unroll
        for (int r = 0; r < 4; ++r) {
          const float v = __builtin_amdgcn_exp2f(fmaf(acc[mi][mi][r], K1, -K1));
          if (l15 == q * 4 + r) Srow[mi][r] -= v;
        }
    }
  }
  __syncthreads();  // drains prefetch into Ls[1]; Ls[0] reads complete

  int buf = 1;
  for (int i = first; i < ntiles; ++i) {
    if (i + 1 < ntiles) stage(cb0 + i + 1, Ls[buf ^ 1]);  // overlaps compute
    const int cb = cb0 + i;
    const int C0 = cb * 128;
    const ushort* Bp = Ls[buf];

    f32x4 acc[4][4];
#pragma unroll
    for (int mi = 0; mi < 4; ++mi)
#pragma unroll
      for (int ni = 0; ni < 4; ++ni)
        acc[mi][ni] = (f32x4){0.f, 0.f, 0.f, 0.f};
#pragma unroll
    for (int ks = 0; ks < 4; ++ks) {
      const int ck = ks * 4 + q;
      bf16x8 bf[4];
#pragma unroll
      for (int ni = 0; ni < 4; ++ni) {
        const int nl = wc * 64 + ni * 16 + l15;
        bf[ni] = *reinterpret_cast<const bf16x8*>(Bp + (nl * 16 + (ck ^ (nl & 15))) * 8);
      }
#pragma unroll
      for (int mi = 0; mi < 4; ++mi)
#pragma unroll
        for (int ni = 0; ni < 4; ++ni)
          acc[mi][ni] = __builtin_amdgcn_mfma_f32_16x16x32_bf16(
              af[mi][ks], bf[ni], acc[mi][ni], 0, 0, 0);
    }

    // Clean epilogue: no per-element masks in the hot loop.
    float Scol[4] = {0.f, 0.f, 0.f, 0.f};
#pragma unroll
    for (int mi = 0; mi < 4; ++mi)
#pragma unroll
      for (int ni = 0; ni < 4; ++ni)
#pragma unroll
        for (int r = 0; r < 4; ++r) {
          const float v = __builtin_amdgcn_exp2f(fmaf(acc[mi][ni][r], K1, -K1));
          Srow[mi][r] += v;
          Scol[ni] += v;
        }

    // Col sums (symmetric contribution): reduce over q, one atomic set/tile.
#pragma unroll
    for (int ni = 0; ni < 4; ++ni) {
      float v = Scol[ni];
      v += __shfl_xor(v, 16, 64);
      v += __shfl_xor(v, 32, 64);
      if (q == 0)
        atomicAdd(&S[C0 + wc * 64 + ni * 16 + l15], v);
    }

    // Positive-pair extraction (uniform branch; one tile per 32 blocks).
    if (cb == rb + 32) {
#pragma unroll
      for (int mi = 0; mi < 4; ++mi)
#pragma unroll
        for (int ni = 0; ni < 4; ++ni)
#pragma unroll
          for (int r = 0; r < 4; ++r) {
            const int rl = wr * 64 + mi * 16 + q * 4 + r;
            const int cl = wc * 64 + ni * 16 + l15;
            if (rl == cl) {
              const float p = 2.0f * acc[mi][ni][r];
              P[R0 + rl] = p;
              P[C0 + cl] = p;
            }
          }
    }

    __syncthreads();  // next-stage drained; this buf's ds_reads complete
    buf ^= 1;
  }

  // Row sums accumulated across the whole strip: one atomic set per block.
#pragma unroll
  for (int mi = 0; mi < 4; ++mi)
#pragma unroll
    for (int r = 0; r < 4; ++r) {
      float v = Srow[mi][r];
      v += __shfl_xor(v, 1, 64);
      v += __shfl_xor(v, 2, 64);
      v += __shfl_xor(v, 4, 64);
      v += __shfl_xor(v, 8, 64);
      if (l15 == 0)
        atomicAdd(&S[R0 + wr * 64 + mi * 16 + q * 4 + r], v);
    }
}

// ---------------------------------------------------------------------------
// Kernel 3: loss = mean_i( 2 + log(S_i) - P_i ). Single block, direct write.
// ---------------------------------------------------------------------------
__global__ __launch_bounds__(1024) void finalize_kernel(
    const float* __restrict__ S, const float* __restrict__ P,
    float* __restrict__ out)
{
  float c = 0.f;
  for (int i = threadIdx.x; i < NROWS; i += 1024)
    c += 2.0f + logf(S[i]) - P[i];
#pragma unroll
  for (int off = 1; off < 64; off <<= 1)
    c += __shfl_xor(c, off, 64);
  __shared__ float wsum[16];
  const int lane = threadIdx.x & 63, w = threadIdx.x >> 6;
  if (lane == 0) wsum[w] = c;
  __syncthreads();
  if (threadIdx.x == 0) {
    float s = 0.f;
#pragma unroll
    for (int k = 0; k < 16; ++k) s += wsum[k];
    out[0] = s * (1.0f / NROWS);
  }
}

// ---------------------------------------------------------------------------
extern "C" void kernel_launch(void* const* d_in, const int* in_sizes, int n_in,
                              void* d_out, int out_size, void* d_ws, size_t ws_size,
                              hipStream_t stream)
{
  const float* zx = (const float*)d_in[0];
  const float* zy = (const float*)d_in[1];
  ushort* zn = (ushort*)d_ws;                                   // 2 MiB bf16
  float*  S  = (float*)((char*)d_ws + (size_t)NROWS * DIM * 2); // 32 KiB
  float*  P  = S + NROWS;                                       // 32 KiB
  float*  out = (float*)d_out;

  normalize_kernel<<<NROWS / 4, 256, 0, stream>>>(zx, zy, zn, S);
  simloss_kernel<<<dim3(64, 16), 256, 0, stream>>>(zn, S, P);
  finalize_kernel<<<1, 1024, 0, stream>>>(S, P, out);
}